// Round 4
// baseline (302.848 us; speedup 1.0000x reference)
//
#include <hip/hip_runtime.h>
#include <math.h>

#define NTOK  16384   // 4 * 4096 tokens
#define DK    2048    // d_model
#define NEXP  64
#define MTOK  64      // tokens per block
#define NWAVE 8       // waves per block; K split 8-way across waves
#define KSL   (DK / NWAVE)   // 256 k per wave
#define KC    16      // k per staged chunk
#define NCH   (KSL / KC)     // 16 chunks

// Async global->LDS, 16B/lane: HW writes dst + lane*16 (wave-uniform dst base).
__device__ __forceinline__ void gload_lds16(const float* src, float* dst) {
    __builtin_amdgcn_global_load_lds(
        (const __attribute__((address_space(1))) void*)src,
        (__attribute__((address_space(3))) void*)dst, 16, 0, 0);
}

__global__ __launch_bounds__(512, 2) void topk_router_kernel(
    const float* __restrict__ x,     // [NTOK][DK]
    const float* __restrict__ Wg,    // [NEXP][DK]
    float* __restrict__ out)         // [NTOK*2] indices (as float) ++ [NTOK*2] weights
{
    // smem: first 32768 floats = 8 waves x 16KB wave-private staging
    //       (dbuf x (x-tile[64][16] ++ W-tile[64][16])).
    // After the epilogue barrier, reused as lg[8][64][68] partial logits.
    __shared__ float smem[34816];    // 139 KiB

    const int tid  = threadIdx.x;
    const int w    = tid >> 6;       // wave 0..7 -> K-slice
    const int lane = tid & 63;
    const int lm   = lane >> 3;      // token-octet: tokens lm*8 .. +7
    const int ln   = lane & 7;       // expert-octet: experts ln*8 .. +7
    const int tok0 = blockIdx.x * MTOK;
    const int k0   = w * KSL;

    float* wreg = smem + w * 4096;   // this wave's private staging (16 KiB)

    // staging lane decomposition: 64 granules/instr = 16 rows x 4 k-quads
    const int srow = lane >> 2;      // row-within-16
    const int sq4  = (lane & 3) * 4; // k word-quad offset

    float acc[8][8];
    #pragma unroll
    for (int i = 0; i < 8; ++i)
        #pragma unroll
        for (int j = 0; j < 8; ++j) acc[i][j] = 0.f;

    // XOR swizzle: LDS[row][q] holds global k = kc + (q ^ ((row>>3)&3)<<2).
    // Stage applies it on the global SOURCE (dest linear for global_load_lds),
    // read applies it again -> cancels (involution). Read-side: a-rows lm*8+i
    // share swA=(lm&3)<<2, b-rows ln*8+j share swB=(ln&3)<<2 -> 8 distinct rows
    // spread 2-per-quad = 2-way conflict = free.
    auto stage = [&](int c, int buf) {
        const int kc = k0 + c * KC;
        float* dstx = wreg + buf * 2048;
        float* dstw = dstx + 1024;
        #pragma unroll
        for (int it = 0; it < 4; ++it) {
            const int row = it * 16 + srow;
            const int wo  = kc + (sq4 ^ (((row >> 3) & 3) << 2));
            gload_lds16(&x [(size_t)(tok0 + row) * DK + wo], dstx + it * 256);
            gload_lds16(&Wg[(size_t)row * DK + wo],          dstw + it * 256);
        }
    };

    auto compute = [&](int buf) {
        const float* xb = wreg + buf * 2048;
        const float* wb = xb + 1024;
        const int swA = (lm & 3) << 2;
        const int swB = (ln & 3) << 2;
        #pragma unroll
        for (int kg = 0; kg < 4; ++kg) {
            float4 a[8], b[8];
            #pragma unroll
            for (int i = 0; i < 8; ++i)
                a[i] = *(const float4*)&xb[(lm * 8 + i) * 16 + ((kg * 4) ^ swA)];
            #pragma unroll
            for (int j = 0; j < 8; ++j)
                b[j] = *(const float4*)&wb[(ln * 8 + j) * 16 + ((kg * 4) ^ swB)];
            #pragma unroll
            for (int i = 0; i < 8; ++i)
                #pragma unroll
                for (int j = 0; j < 8; ++j) {
                    acc[i][j] = fmaf(a[i].x, b[j].x, acc[i][j]);
                    acc[i][j] = fmaf(a[i].y, b[j].y, acc[i][j]);
                    acc[i][j] = fmaf(a[i].z, b[j].z, acc[i][j]);
                    acc[i][j] = fmaf(a[i].w, b[j].w, acc[i][j]);
                }
        }
    };

    // ---- prologue: 2 chunks in flight (8 loads each) ----
    stage(0, 0);
    stage(1, 1);

    // ---- main loop: no barriers; counted vmcnt keeps 8-16 loads in flight ----
    #pragma unroll 1
    for (int c = 0; c < NCH - 1; ++c) {
        asm volatile("s_waitcnt vmcnt(8)" ::: "memory");  // chunk c landed
        __builtin_amdgcn_sched_barrier(0);
        compute(c & 1);
        if (c + 2 < NCH) stage(c + 2, c & 1);   // refill buffer just freed
    }
    asm volatile("s_waitcnt vmcnt(0)" ::: "memory");
    __builtin_amdgcn_sched_barrier(0);
    compute((NCH - 1) & 1);

    // ---- combine 8 K-partials (the only barriers) ----
    __syncthreads();
    {
        float* lg = smem;   // [8][64][68]
        #pragma unroll
        for (int i = 0; i < 8; ++i) {
            float* rowp = lg + ((w * 64) + (lm * 8 + i)) * 68 + ln * 8;
            *(float4*)(rowp)     = make_float4(acc[i][0], acc[i][1], acc[i][2], acc[i][3]);
            *(float4*)(rowp + 4) = make_float4(acc[i][4], acc[i][5], acc[i][6], acc[i][7]);
        }
    }
    __syncthreads();

    // ---- top-2 per token: wave w -> tokens w*8..w*8+7, lane = expert ----
    #pragma unroll 1
    for (int t = 0; t < 8; ++t) {
        const int tok = w * 8 + t;
        float v = 0.f;
        #pragma unroll
        for (int p = 0; p < 8; ++p) v += smem[(p * 64 + tok) * 68 + lane];

        // top-1 (tie -> lower index, matching lax.top_k)
        float m1 = v; int i1 = lane;
        #pragma unroll
        for (int off = 32; off > 0; off >>= 1) {
            float ov = __shfl_xor(m1, off);
            int   oi = __shfl_xor(i1, off);
            if (ov > m1 || (ov == m1 && oi < i1)) { m1 = ov; i1 = oi; }
        }
        // top-2: mask out winner
        float m2 = (lane == i1) ? -INFINITY : v; int i2 = lane;
        #pragma unroll
        for (int off = 32; off > 0; off >>= 1) {
            float ov = __shfl_xor(m2, off);
            int   oi = __shfl_xor(i2, off);
            if (ov > m2 || (ov == m2 && oi < i2)) { m2 = ov; i2 = oi; }
        }

        if (lane == 0) {
            const int gtok = tok0 + tok;
            // softmax denom cancels: w1 = 1/(1+e^{l2-l1}), w2 = 1 - w1
            const float e  = expf(m2 - m1);
            const float w1 = 1.0f / (1.0f + e);
            const float w2 = e / (1.0f + e);
            out[gtok * 2 + 0] = (float)i1;
            out[gtok * 2 + 1] = (float)i2;
            out[NTOK * 2 + gtok * 2 + 0] = w1;
            out[NTOK * 2 + gtok * 2 + 1] = w2;
        }
    }
}

extern "C" void kernel_launch(void* const* d_in, const int* in_sizes, int n_in,
                              void* d_out, int out_size, void* d_ws, size_t ws_size,
                              hipStream_t stream) {
    const float* x  = (const float*)d_in[0];
    const float* Wg = (const float*)d_in[1];
    float* out = (float*)d_out;
    // 256 blocks x 512 threads = 2048 waves (2/SIMD), 1 block/CU, barrier-free K-loop.
    hipLaunchKernelGGL(topk_router_kernel, dim3(NTOK / MTOK), dim3(512), 0, stream,
                       x, Wg, out);
}